// Round 1
// baseline (394.273 us; speedup 1.0000x reference)
//
#include <hip/hip_runtime.h>
#include <math.h>

// Problem constants (B=2,S=2048,D=768,E=8,F=3072)
#define T_TOK 4096
#define DDIM  768
#define EXP   8
#define FDIM  3072

typedef __bf16 bf16x8 __attribute__((ext_vector_type(8)));
typedef float  f32x4  __attribute__((ext_vector_type(4)));

__device__ __forceinline__ ushort f2bf(float f) {
    union { float f; unsigned u; } v; v.f = f;
    unsigned r = v.u + 0x7fffu + ((v.u >> 16) & 1u);   // RNE
    return (ushort)(r >> 16);
}

// ---------------- router: logits f32, gate+argmax, token lists, x->bf16 ----
__global__ __launch_bounds__(256) void router_kernel(
    const float* __restrict__ x, const float* __restrict__ Wr,
    int* __restrict__ counts, int* __restrict__ tlist,
    float* __restrict__ gates, ushort* __restrict__ xb)
{
    const int lane = threadIdx.x & 63;
    const int wv   = threadIdx.x >> 6;
    const int t    = blockIdx.x * 4 + wv;          // grid 1024 * 4 waves = 4096
    const float* xr = x + (size_t)t * DDIM;
    float xv[12];
#pragma unroll
    for (int i = 0; i < 12; ++i) xv[i] = xr[lane + 64 * i];
#pragma unroll
    for (int i = 0; i < 12; ++i) xb[(size_t)t * DDIM + lane + 64 * i] = f2bf(xv[i]);

    float acc[EXP];
#pragma unroll
    for (int e = 0; e < EXP; ++e) {
        const float* wr = Wr + e * DDIM;
        float a = 0.f;
#pragma unroll
        for (int i = 0; i < 12; ++i) a += xv[i] * wr[lane + 64 * i];
        acc[e] = a;
    }
#pragma unroll
    for (int off = 32; off > 0; off >>= 1) {
#pragma unroll
        for (int e = 0; e < EXP; ++e) acc[e] += __shfl_xor(acc[e], off);
    }
    if (lane == 0) {
        // complexity bias is uniform over experts -> softmax/argmax invariant
        float m = acc[0]; int am = 0;
#pragma unroll
        for (int e = 1; e < EXP; ++e) if (acc[e] > m) { m = acc[e]; am = e; }
        float s = 0.f;
#pragma unroll
        for (int e = 0; e < EXP; ++e) s += expf(acc[e] - m);
        gates[t] = 1.0f / s;                        // max(softmax) = 1/sum exp(l-max)
        int pos = atomicAdd(&counts[am], 1);
        tlist[am * T_TOK + pos] = t;
    }
}

// ---------------- grouped GEMM: C[m,n] = sum_k A[t_m,k] * W[e,n,k] ---------
// MODE 1: A=xb (bf16), W=W1 (f32), epilogue exact-erf GELU -> H bf16
// MODE 2: A=h  (bf16), W=W2 (f32), epilogue *gate -> Out f32
template <int NTOT, int KTOT, int MODE>
__global__ __launch_bounds__(256, 2) void moe_gemm(
    const ushort* __restrict__ A, const float* __restrict__ W,
    ushort* __restrict__ H, float* __restrict__ Out,
    const int* __restrict__ counts, const int* __restrict__ tlist,
    const float* __restrict__ gates)
{
    const int e  = blockIdx.z;
    const int Ne = counts[e];
    const int m0 = blockIdx.y * 128;
    if (m0 >= Ne) return;
    const int n0 = blockIdx.x * 128;

    __shared__ ushort As[128 * 64];
    __shared__ ushort Bs[128 * 64];

    const int tid  = threadIdx.x;
    const int lane = tid & 63;
    const int wv   = tid >> 6;
    const int wrow = (wv >> 1) * 64;
    const int wcol = (wv & 1) * 64;
    const int* tl  = tlist + e * T_TOK;

    f32x4 acc[4][4];
#pragma unroll
    for (int m = 0; m < 4; ++m)
#pragma unroll
        for (int n = 0; n < 4; ++n) acc[m][n] = (f32x4)0.f;

    for (int kt = 0; kt < KTOT / 64; ++kt) {
        const int k0 = kt * 64;
        if (kt) __syncthreads();
        // ---- stage A: 128 rows x 64 bf16, gathered rows, 16B/unit --------
#pragma unroll
        for (int i = 0; i < 4; ++i) {
            int u = i * 256 + tid;
            int r = u >> 3, uc = u & 7;
            int slot = m0 + r; if (slot > Ne - 1) slot = Ne - 1;
            int t = tl[slot];
            uint4 v = *(const uint4*)(A + (size_t)t * KTOT + k0 + uc * 8);
            int b = (r * 128 + uc * 16) ^ ((r & 7) << 4);     // XOR swizzle
            *(uint4*)((char*)As + b) = v;
        }
        // ---- stage B: 128 n-rows x 64 k, f32 -> bf16 convert -------------
        const float* Wb = W + ((size_t)e * NTOT + n0) * KTOT + k0;
#pragma unroll
        for (int i = 0; i < 4; ++i) {
            int u = i * 256 + tid;
            int r = u >> 3, uc = u & 7;
            const float4* src = (const float4*)(Wb + (size_t)r * KTOT + uc * 8);
            float4 v0 = src[0], v1 = src[1];
            uint4 p;
            p.x = (unsigned)f2bf(v0.x) | ((unsigned)f2bf(v0.y) << 16);
            p.y = (unsigned)f2bf(v0.z) | ((unsigned)f2bf(v0.w) << 16);
            p.z = (unsigned)f2bf(v1.x) | ((unsigned)f2bf(v1.y) << 16);
            p.w = (unsigned)f2bf(v1.z) | ((unsigned)f2bf(v1.w) << 16);
            int b = (r * 128 + uc * 16) ^ ((r & 7) << 4);
            *(uint4*)((char*)Bs + b) = p;
        }
        __syncthreads();
        // ---- MFMA: 2 ksubs x (4 A frags, 4 B frags, 16 mfma) -------------
#pragma unroll
        for (int ks = 0; ks < 2; ++ks) {
            const int kb = (ks * 32 + (lane >> 4) * 8) * 2;   // byte col offset
            bf16x8 af[4], bfr[4];
#pragma unroll
            for (int m = 0; m < 4; ++m) {
                int r = wrow + m * 16 + (lane & 15);
                int b = (r * 128 + kb) ^ ((r & 7) << 4);
                af[m] = *(const bf16x8*)((const char*)As + b);
            }
#pragma unroll
            for (int n = 0; n < 4; ++n) {
                int r = wcol + n * 16 + (lane & 15);
                int b = (r * 128 + kb) ^ ((r & 7) << 4);
                bfr[n] = *(const bf16x8*)((const char*)Bs + b);
            }
#pragma unroll
            for (int m = 0; m < 4; ++m)
#pragma unroll
                for (int n = 0; n < 4; ++n)
                    acc[m][n] = __builtin_amdgcn_mfma_f32_16x16x32_bf16(
                        af[m], bfr[n], acc[m][n], 0, 0, 0);
        }
    }
    // ---- epilogue: C frag (row=(lane>>4)*4+j, col=lane&15) [m89 layout] ---
    const int lr4 = (lane >> 4) * 4, lc = lane & 15;
#pragma unroll
    for (int m = 0; m < 4; ++m) {
        const int rbase = wrow + m * 16 + lr4;
#pragma unroll
        for (int j = 0; j < 4; ++j) {
            const int slot = m0 + rbase + j;
            if (slot >= Ne) continue;
            const int t = tl[slot];
            const float g = (MODE == 2) ? gates[t] : 0.f;
#pragma unroll
            for (int n = 0; n < 4; ++n) {
                float v = acc[m][n][j];
                const int c = n0 + wcol + n * 16 + lc;
                if (MODE == 1) {
                    float gv = 0.5f * v * (1.0f + erff(v * 0.70710678118654752f));
                    H[(size_t)t * NTOT + c] = f2bf(gv);
                } else {
                    Out[(size_t)t * NTOT + c] = v * g;
                }
            }
        }
    }
}

// ---------------- finalize: lb_loss, counts, avg gate, active --------------
__global__ __launch_bounds__(256) void finalize_kernel(
    const float* __restrict__ gates, const int* __restrict__ counts,
    float* __restrict__ tail)
{
    __shared__ float red[256];
    float s = 0.f;
    for (int i = threadIdx.x; i < T_TOK; i += 256) s += gates[i];
    red[threadIdx.x] = s;
    __syncthreads();
    for (int off = 128; off > 0; off >>= 1) {
        if (threadIdx.x < off) red[threadIdx.x] += red[threadIdx.x + off];
        __syncthreads();
    }
    if (threadIdx.x == 0) {
        float lb = 0.f; int active = 0;
#pragma unroll
        for (int e = 0; e < EXP; ++e) {
            float c = (float)counts[e];
            float d = c - 512.0f;                  // mean is exactly T/E
            lb += d * d;
            active += (counts[e] > 0) ? 1 : 0;
        }
        tail[0] = lb * (0.01f / 8.0f);             // lb_loss
#pragma unroll
        for (int e = 0; e < EXP; ++e) tail[1 + e] = (float)counts[e];
        tail[9]  = red[0] / (float)T_TOK;          // average_gate
        tail[10] = (float)active;                  // active_experts
    }
}

// ---------------- launch ---------------------------------------------------
extern "C" void kernel_launch(void* const* d_in, const int* in_sizes, int n_in,
                              void* d_out, int out_size, void* d_ws, size_t ws_size,
                              hipStream_t stream)
{
    const float* x  = (const float*)d_in[0];
    const float* Wr = (const float*)d_in[2];
    const float* W1 = (const float*)d_in[5];
    const float* W2 = (const float*)d_in[6];
    float* out = (float*)d_out;

    // workspace layout (~31.6 MB)
    char* ws = (char*)d_ws;
    int*    counts = (int*)ws;                               // 32 B
    int*    tlist  = (int*)(ws + 256);                       // 128 KiB
    float*  gates  = (float*)(ws + 256 + 131072);            // 16 KiB
    ushort* xb     = (ushort*)(ws + 147712);                 // 6.29 MB
    ushort* h      = (ushort*)(ws + 6439168);                // 25.2 MB

    hipMemsetAsync(counts, 0, EXP * sizeof(int), stream);
    router_kernel<<<dim3(T_TOK / 4), dim3(256), 0, stream>>>(x, Wr, counts, tlist, gates, xb);
    moe_gemm<FDIM, DDIM, 1><<<dim3(FDIM / 128, T_TOK / 128, EXP), dim3(256), 0, stream>>>(
        xb, W1, h, nullptr, counts, tlist, gates);
    moe_gemm<DDIM, FDIM, 2><<<dim3(DDIM / 128, T_TOK / 128, EXP), dim3(256), 0, stream>>>(
        h, W2, nullptr, out, counts, tlist, gates);
    finalize_kernel<<<dim3(1), dim3(256), 0, stream>>>(gates, counts, out + (size_t)T_TOK * DDIM);
}

// Round 2
// 373.807 us; speedup vs baseline: 1.0548x; 1.0548x over previous
//
#include <hip/hip_runtime.h>
#include <math.h>

// Problem constants (B=2,S=2048,D=768,E=8,F=3072)
#define T_TOK 4096
#define DDIM  768
#define EXP   8
#define FDIM  3072

typedef __bf16 bf16x8 __attribute__((ext_vector_type(8)));
typedef float  f32x4  __attribute__((ext_vector_type(4)));

__device__ __forceinline__ ushort f2bf(float f) {
    union { float f; unsigned u; } v; v.f = f;
    unsigned r = v.u + 0x7fffu + ((v.u >> 16) & 1u);   // RNE
    return (ushort)(r >> 16);
}

// async global->LDS, 16B per lane; lptr must be wave-uniform (HW adds lane*16)
__device__ __forceinline__ void gl_lds16(const void* g, void* l) {
    __builtin_amdgcn_global_load_lds(
        (__attribute__((address_space(1))) void*)(g),
        (__attribute__((address_space(3))) void*)(l), 16, 0, 0);
}

// ---------------- router: logits f32, gate+argmax, token lists, x->bf16 ----
__global__ __launch_bounds__(256) void router_kernel(
    const float* __restrict__ x, const float* __restrict__ Wr,
    int* __restrict__ counts, int* __restrict__ tlist,
    float* __restrict__ gates, ushort* __restrict__ xb)
{
    const int lane = threadIdx.x & 63;
    const int wv   = threadIdx.x >> 6;
    const int t    = blockIdx.x * 4 + wv;          // grid 1024 * 4 waves = 4096
    const float* xr = x + (size_t)t * DDIM;
    float xv[12];
#pragma unroll
    for (int i = 0; i < 12; ++i) xv[i] = xr[lane + 64 * i];
#pragma unroll
    for (int i = 0; i < 12; ++i) xb[(size_t)t * DDIM + lane + 64 * i] = f2bf(xv[i]);

    float acc[EXP];
#pragma unroll
    for (int e = 0; e < EXP; ++e) {
        const float* wr = Wr + e * DDIM;
        float a = 0.f;
#pragma unroll
        for (int i = 0; i < 12; ++i) a += xv[i] * wr[lane + 64 * i];
        acc[e] = a;
    }
#pragma unroll
    for (int off = 32; off > 0; off >>= 1) {
#pragma unroll
        for (int e = 0; e < EXP; ++e) acc[e] += __shfl_xor(acc[e], off);
    }
    if (lane == 0) {
        // complexity bias is uniform over experts -> softmax/argmax invariant
        float m = acc[0]; int am = 0;
#pragma unroll
        for (int e = 1; e < EXP; ++e) if (acc[e] > m) { m = acc[e]; am = e; }
        float s = 0.f;
#pragma unroll
        for (int e = 0; e < EXP; ++e) s += expf(acc[e] - m);
        gates[t] = 1.0f / s;                        // max(softmax) = 1/sum exp(l-max)
        int pos = atomicAdd(&counts[am], 1);
        tlist[am * T_TOK + pos] = t;
    }
}

// ---------------- weight convert: f32 -> bf16, vectorized ------------------
__global__ __launch_bounds__(256) void convert_kernel(
    const float* __restrict__ src, ushort* __restrict__ dst, int n8)
{
    int i = blockIdx.x * blockDim.x + threadIdx.x;
    const int stride = gridDim.x * blockDim.x;
    for (; i < n8; i += stride) {
        const float4* s = (const float4*)(src + (size_t)i * 8);
        float4 a = s[0], b = s[1];
        uint4 p;
        p.x = (unsigned)f2bf(a.x) | ((unsigned)f2bf(a.y) << 16);
        p.y = (unsigned)f2bf(a.z) | ((unsigned)f2bf(a.w) << 16);
        p.z = (unsigned)f2bf(b.x) | ((unsigned)f2bf(b.y) << 16);
        p.w = (unsigned)f2bf(b.z) | ((unsigned)f2bf(b.w) << 16);
        ((uint4*)dst)[i] = p;
    }
}

// ---------------- grouped GEMM (m97 structure): C = A[t,:] * W[e,n,:]^T ----
// MODE 1: A=xb bf16, W=W1b, GELU -> H bf16.  MODE 2: A=h, W=W2b, *gate -> Out f32
template <int BM, int NTOT, int KTOT, int MODE>
__global__ __launch_bounds__(256, 3) void moe_gemm(
    const ushort* __restrict__ A, const ushort* __restrict__ W,
    ushort* __restrict__ H, float* __restrict__ Out,
    const int* __restrict__ counts, const int* __restrict__ tlist,
    const float* __restrict__ gates)
{
    constexpr int NCH = BM / 8 + 16;     // 1KB LDS chunks: A = BM/8, B = 16
    constexpr int CPW = NCH / 4;         // chunks per wave
    constexpr int MR  = BM / 32;         // 16-row frags per wave (m dim)

    const int e  = blockIdx.z;
    const int Ne = counts[e];
    const int m0 = blockIdx.y * BM;
    if (m0 >= Ne) return;
    const int n0 = blockIdx.x * 128;

    __shared__ ushort S[(BM + 128) * 64];
    char* Sb = (char*)S;

    const int tid  = threadIdx.x;
    const int lane = tid & 63;
    const int wv   = tid >> 6;
    const int* tl  = tlist + e * T_TOK;

    // per-lane global base pointers for this wave's staging chunks
    const ushort* bp[CPW];
#pragma unroll
    for (int i = 0; i < CPW; ++i) {
        const int c = wv * CPW + i;
        if (c < BM / 8) {
            int slot = m0 + c * 8 + (lane >> 3);
            if (slot > Ne - 1) slot = Ne - 1;
            bp[i] = A + (size_t)tl[slot] * KTOT + (lane & 7) * 8;
        } else {
            const int r = (c - BM / 8) * 8 + (lane >> 3);
            bp[i] = W + ((size_t)e * NTOT + n0 + r) * KTOT + (lane & 7) * 8;
        }
    }

    f32x4 acc[MR][4];
#pragma unroll
    for (int m = 0; m < MR; ++m)
#pragma unroll
        for (int n = 0; n < 4; ++n) acc[m][n] = (f32x4)0.f;

    const int wrow = (wv >> 1) * (BM / 2);
    const int wcol = (wv & 1) * 64;

    for (int kt = 0; kt < KTOT / 64; ++kt) {
        if (kt) __syncthreads();
#pragma unroll
        for (int i = 0; i < CPW; ++i)
            gl_lds16(bp[i] + kt * 64, Sb + (wv * CPW + i) * 1024);
        __syncthreads();                 // drains vmcnt before ds_read
#pragma unroll
        for (int ks = 0; ks < 2; ++ks) {
            const int kb = (ks * 32 + (lane >> 4) * 8) * 2;
            bf16x8 af[MR], bfr[4];
#pragma unroll
            for (int m = 0; m < MR; ++m) {
                const int r = wrow + m * 16 + (lane & 15);
                af[m] = *(const bf16x8*)(Sb + r * 128 + kb);
            }
#pragma unroll
            for (int n = 0; n < 4; ++n) {
                const int r = wcol + n * 16 + (lane & 15);
                bfr[n] = *(const bf16x8*)(Sb + BM * 128 + r * 128 + kb);
            }
#pragma unroll
            for (int m = 0; m < MR; ++m)
#pragma unroll
                for (int n = 0; n < 4; ++n)
                    acc[m][n] = __builtin_amdgcn_mfma_f32_16x16x32_bf16(
                        af[m], bfr[n], acc[m][n], 0, 0, 0);
        }
    }

    // epilogue: C frag row=(lane>>4)*4+j, col=lane&15  [m89 layout]
    const int lr4 = (lane >> 4) * 4, lc = lane & 15;
#pragma unroll
    for (int m = 0; m < MR; ++m) {
        const int rbase = wrow + m * 16 + lr4;
#pragma unroll
        for (int j = 0; j < 4; ++j) {
            const int slot = m0 + rbase + j;
            if (slot >= Ne) continue;
            const int t = tl[slot];
            const float g = (MODE == 2) ? gates[t] : 0.f;
#pragma unroll
            for (int n = 0; n < 4; ++n) {
                float v = acc[m][n][j];
                const int c = n0 + wcol + n * 16 + lc;
                if (MODE == 1) {
                    float gv = 0.5f * v * (1.0f + erff(v * 0.70710678118654752f));
                    H[(size_t)t * NTOT + c] = f2bf(gv);
                } else {
                    Out[(size_t)t * NTOT + c] = v * g;
                }
            }
        }
    }
}

// ---------------- finalize: lb_loss, counts, avg gate, active --------------
__global__ __launch_bounds__(256) void finalize_kernel(
    const float* __restrict__ gates, const int* __restrict__ counts,
    float* __restrict__ tail)
{
    __shared__ float red[256];
    float s = 0.f;
    for (int i = threadIdx.x; i < T_TOK; i += 256) s += gates[i];
    red[threadIdx.x] = s;
    __syncthreads();
    for (int off = 128; off > 0; off >>= 1) {
        if (threadIdx.x < off) red[threadIdx.x] += red[threadIdx.x + off];
        __syncthreads();
    }
    if (threadIdx.x == 0) {
        float lb = 0.f; int active = 0;
#pragma unroll
        for (int e = 0; e < EXP; ++e) {
            float c = (float)counts[e];
            float d = c - 512.0f;                  // mean is exactly T/E
            lb += d * d;
            active += (counts[e] > 0) ? 1 : 0;
        }
        tail[0] = lb * (0.01f / 8.0f);             // lb_loss
#pragma unroll
        for (int e = 0; e < EXP; ++e) tail[1 + e] = (float)counts[e];
        tail[9]  = red[0] / (float)T_TOK;          // average_gate
        tail[10] = (float)active;                  // active_experts
    }
}

// ---------------- launch ---------------------------------------------------
extern "C" void kernel_launch(void* const* d_in, const int* in_sizes, int n_in,
                              void* d_out, int out_size, void* d_ws, size_t ws_size,
                              hipStream_t stream)
{
    const float* x  = (const float*)d_in[0];
    const float* Wr = (const float*)d_in[2];
    const float* W1 = (const float*)d_in[5];
    const float* W2 = (const float*)d_in[6];
    float* out = (float*)d_out;

    // workspace layout (~69.4 MB peak); wb is shared by W1b then W2b
    char* ws = (char*)d_ws;
    int*    counts = (int*)ws;                     // 32 B (pad 256)
    int*    tlist  = (int*)(ws + 256);             // 128 KiB
    float*  gates  = (float*)(ws + 131328);        // 16 KiB
    ushort* xb     = (ushort*)(ws + 147712);       // 6.29 MB
    ushort* h      = (ushort*)(ws + 6439168);      // 25.2 MB
    ushort* wb     = (ushort*)(ws + 31604992);     // 37.75 MB (shared)

    const int W8 = (EXP * FDIM * DDIM) / 8;        // 2359296 units of 8 floats

    hipMemsetAsync(counts, 0, EXP * sizeof(int), stream);
    router_kernel<<<dim3(T_TOK / 4), dim3(256), 0, stream>>>(x, Wr, counts, tlist, gates, xb);

    convert_kernel<<<dim3(2048), dim3(256), 0, stream>>>(W1, wb, W8);
    moe_gemm<128, FDIM, DDIM, 1><<<dim3(FDIM / 128, T_TOK / 128, EXP), dim3(256), 0, stream>>>(
        xb, wb, h, nullptr, counts, tlist, gates);

    convert_kernel<<<dim3(2048), dim3(256), 0, stream>>>(W2, wb, W8);
    moe_gemm<64, DDIM, FDIM, 2><<<dim3(DDIM / 128, T_TOK / 64, EXP), dim3(256), 0, stream>>>(
        h, wb, nullptr, out, counts, tlist, gates);

    finalize_kernel<<<dim3(1), dim3(256), 0, stream>>>(gates, counts, out + (size_t)T_TOK * DDIM);
}